// Round 7
// baseline (97.938 us; speedup 1.0000x reference)
//
#include <hip/hip_runtime.h>
#include <hip/hip_bf16.h>

typedef unsigned short u16;
typedef float  floatx4 __attribute__((ext_vector_type(4)));
typedef short  bf16x8  __attribute__((ext_vector_type(8)));

#define GK 4352   // 4096 + 64 lora cols + 192 zero pad (= 4 * 17 * 64)

__device__ __forceinline__ u16 f2bf_rne(float f) {
  union { float f; unsigned int u; } v; v.f = f;
  unsigned int r = v.u + 0x7FFFu + ((v.u >> 16) & 1u);
  return (u16)(r >> 16);
}
__device__ __forceinline__ float bf2f(u16 h) {
  union { unsigned int u; float f; } v; v.u = ((unsigned int)h) << 16;
  return v.f;
}

// ===========================================================================
// In-register FWHT-4096 per block (4 waves): H4096 = H64(rows) (x) H64(cols).
// ===========================================================================
__device__ __forceinline__ void fwht4096_regs(float v[16], float* X, int w, int l) {
#pragma unroll
  for (int h = 1; h < 64; h <<= 1) {
#pragma unroll
    for (int k = 0; k < 16; ++k) {
      float o = __shfl_xor(v[k], h, 64);
      v[k] = (l & h) ? (o - v[k]) : (v[k] + o);
    }
  }
#pragma unroll
  for (int k = 0; k < 16; ++k) X[(w * 16 + k) * 64 + l] = v[k];
  __syncthreads();
  float s4 = (w & 1) ? -1.f : 1.f;
  float s5 = (w & 2) ? -1.f : 1.f;
#pragma unroll
  for (int k = 0; k < 16; ++k) {
    float x00 = X[(k     ) * 64 + l];
    float x01 = X[(k + 16) * 64 + l];
    float x10 = X[(k + 32) * 64 + l];
    float x11 = X[(k + 48) * 64 + l];
    v[k] = (x00 + s4 * x01) + s5 * (x10 + s4 * x11);
  }
#pragma unroll
  for (int h = 1; h < 16; h <<= 1) {
#pragma unroll
    for (int k = 0; k < 16; ++k) {
      if (!(k & h)) { float a = v[k], b = v[k ^ h]; v[k] = a + b; v[k ^ h] = a - b; }
    }
  }
}

// ---------------------------------------------------------------------------
// Kernel 1: decode E8P -> integer weights (exact in bf16), pitched rows of GK.
// ---------------------------------------------------------------------------
__global__ void decode_kernel(const int* __restrict__ codes,
                              const int* __restrict__ grid,
                              u16* __restrict__ Wd) {
  __shared__ int sgrid[256];
  int t = threadIdx.x;
  sgrid[t] = grid[t & 255];
  __syncthreads();
  int idx = blockIdx.x * 256 + t;            // 0 .. 4096*512-1
  int c = codes[idx];
  int abs_idx   = c & 255;
  int sign_bits = (c >> 8) & 127;
  int dlt       = 2 * ((c >> 15) & 1) - 1;   // 4*delta = ±1
  int packed    = sgrid[abs_idx];
  int par       = __popc(sign_bits) & 1;
  u16 w[8];
#pragma unroll
  for (int j = 0; j < 8; ++j) {
    int nib = (packed >> (4 * j)) & 15;
    int neg = (j < 7) ? ((sign_bits >> j) & 1) : par;
    int val = (neg ? -2 * nib : 2 * nib) + dlt;
    w[j] = f2bf_rne((float)val);             // exact: |val| <= 29
  }
  uint4 pk;
  pk.x = (unsigned)w[0] | ((unsigned)w[1] << 16);
  pk.y = (unsigned)w[2] | ((unsigned)w[3] << 16);
  pk.z = (unsigned)w[4] | ((unsigned)w[5] << 16);
  pk.w = (unsigned)w[6] | ((unsigned)w[7] << 16);
  int m = idx >> 9, g = idx & 511;
  ((uint4*)Wd)[(size_t)m * (GK / 8) + g] = pk;   // GK/8 = 544 uint4 per row
}

// ---------------------------------------------------------------------------
// Kernel 2 (fused): per block r (64 blocks):
//  (a) Wd[:,4096+r] = bf16( (0.8*263.68/(4096*Wscale)) * H_M(SV o loraA[:,r]) )
//  (b) zero Wd rows [64r,64r+64) cols 4160..4351 (K pad)
//  (c) Bh[r][:] = bf16( Hnorm(loraB[r] o SU) )   (Parseval: lr = u . Bh)
// ---------------------------------------------------------------------------
__global__ __launch_bounds__(256) void prep_lora_kernel(
    const float* __restrict__ loraA, const float* __restrict__ SV,
    const float* __restrict__ WscaleP, const float* __restrict__ loraB,
    const float* __restrict__ SU, u16* __restrict__ Wd, u16* __restrict__ Bh) {
  __shared__ float X[4096];
  int r = blockIdx.x, t = threadIdx.x, l = t & 63, w = t >> 6;
  float v[16];
  // (a) loraA column FWHT -> scatter to Wd tail col
#pragma unroll
  for (int k = 0; k < 16; ++k) {
    int i = (w * 16 + k) * 64 + l;
    v[k] = loraA[(size_t)i * 64 + r] * SV[i];
  }
  fwht4096_regs(v, X, w, l);
  float factor = (0.8f * 263.68f / 4096.0f) / WscaleP[0];
#pragma unroll
  for (int k = 0; k < 16; ++k) {
    int i = (w * 16 + k) * 64 + l;
    Wd[(size_t)i * GK + 4096 + r] = f2bf_rne(v[k] * factor);
  }
  // (b) zero K-pad cols 4160..4351 for rows [64r, 64r+64): 64*24 uint4
  {
    uint4 zv = make_uint4(0, 0, 0, 0);
#pragma unroll
    for (int j = 0; j < 6; ++j) {
      int idx = t + 256 * j;                 // 0..1535
      int row = idx / 24, cs = idx % 24;
      uint4* p = (uint4*)(Wd + (size_t)(r * 64 + row) * GK + 4160) + cs;
      *p = zv;
    }
  }
  __syncthreads();
  // (c) loraB row FWHT -> Bh
#pragma unroll
  for (int k = 0; k < 16; ++k) {
    int i = (w * 16 + k) * 64 + l;
    v[k] = loraB[(size_t)r * 4096 + i] * SU[i];
  }
  fwht4096_regs(v, X, w, l);
#pragma unroll
  for (int k = 0; k < 16; ++k) {
    int i = (w * 16 + k) * 64 + l;
    Bh[(size_t)r * 4096 + i] = f2bf_rne(v[k] * 0.015625f);
  }
}

// ---------------------------------------------------------------------------
// Kernel 3: u[s][0..4095] = bf16( H(x[s] o SU) / 64 )
// ---------------------------------------------------------------------------
__global__ __launch_bounds__(256) void fwht_u_kernel(const float* __restrict__ x,
                                                     const float* __restrict__ SU,
                                                     u16* __restrict__ u) {
  __shared__ float X[4096];
  int s = blockIdx.x, t = threadIdx.x, l = t & 63, w = t >> 6;
  const float* xr = x + (size_t)s * 4096;
  float v[16];
#pragma unroll
  for (int k = 0; k < 16; ++k) {
    int i = (w * 16 + k) * 64 + l;
    v[k] = xr[i] * SU[i];
  }
  fwht4096_regs(v, X, w, l);
  u16* ur = u + (size_t)s * GK;
#pragma unroll
  for (int k = 0; k < 16; ++k) {
    int i = (w * 16 + k) * 64 + l;
    ur[i] = f2bf_rne(v[k] * 0.015625f);
  }
}

// ---------------------------------------------------------------------------
// Staging helpers (16B global_load_lds, XOR-swizzled source; verified r2-r6)
// ---------------------------------------------------------------------------
// 128 rows x 64 cols, 4-wave block, pitch GK (lr_gemm A)
__device__ __forceinline__ void stage128(const u16* __restrict__ src, int rowBase,
                                         int kt, char* ldsBase, int wg, int l) {
#pragma unroll
  for (int it = 0; it < 4; ++it) {
    int ci  = it * 4 + wg;
    int row = ci * 8 + (l >> 3);
    int cg  = (l & 7) ^ ((l >> 3) & 7);
    const u16* gp = src + (size_t)(rowBase + row) * GK + kt + cg * 8;
    __builtin_amdgcn_global_load_lds(
        (const __attribute__((address_space(1))) void*)gp,
        (__attribute__((address_space(3))) void*)(ldsBase + ci * 1024), 16, 0, 0);
  }
}
// 64 rows x 64 cols, 4-wave block, pitch 4096 (lr_gemm Bh)
__device__ __forceinline__ void stage64n(const u16* __restrict__ src,
                                         int kt, char* ldsBase, int wg, int l) {
#pragma unroll
  for (int it = 0; it < 2; ++it) {
    int ci  = it * 4 + wg;
    int row = ci * 8 + (l >> 3);
    int cg  = (l & 7) ^ ((l >> 3) & 7);
    const u16* gp = src + (size_t)row * 4096 + kt + cg * 8;
    __builtin_amdgcn_global_load_lds(
        (const __attribute__((address_space(1))) void*)gp,
        (__attribute__((address_space(3))) void*)(ldsBase + ci * 1024), 16, 0, 0);
  }
}
// 256 rows x 64 cols, 8-wave block, pitch GK (main gemm)
__device__ __forceinline__ void stage256(const u16* __restrict__ src, int rowBase,
                                         int kt, char* ldsBase, int w, int l) {
#pragma unroll
  for (int it = 0; it < 4; ++it) {
    int ci  = it * 8 + w;                 // 32 chunks of 1KB
    int row = ci * 8 + (l >> 3);
    int cg  = (l & 7) ^ ((l >> 3) & 7);
    const u16* gp = src + (size_t)(rowBase + row) * GK + kt + cg * 8;
    __builtin_amdgcn_global_load_lds(
        (const __attribute__((address_space(1))) void*)gp,
        (__attribute__((address_space(3))) void*)(ldsBase + ci * 1024), 16, 0, 0);
  }
}

// ---------------------------------------------------------------------------
// Kernel 4: lr partials. P[by][s][r] = sum_{k in chunk by} u[s,k]*Bh[r,k]
// ---------------------------------------------------------------------------
__global__ __launch_bounds__(256) void lr_gemm_kernel(
    const u16* __restrict__ U,    // [1024][GK]
    const u16* __restrict__ Bh,   // [64][4096]
    float* __restrict__ P) {      // [4][1024][64]
  __shared__ char lds[49152];     // A0|A1 (16KB each) + B0|B1 (8KB each)
  int t = threadIdx.x, w = t >> 6, l = t & 63;
  int s0 = blockIdx.x * 128, k0 = blockIdx.y * 1024;
  int lr16 = l & 15, lk = l >> 4;
  char* ldsA = lds;
  char* ldsB = lds + 32768;

  floatx4 acc[2][4];
#pragma unroll
  for (int i = 0; i < 2; ++i)
#pragma unroll
    for (int j = 0; j < 4; ++j) acc[i][j] = (floatx4){0.f, 0.f, 0.f, 0.f};

  const int NT = 16;   // 16 * 64 = 1024
  stage128(U,  s0, k0,      ldsA,         w, l);
  stage64n(Bh,     k0,      ldsB,         w, l);
  stage128(U,  s0, k0 + 64, ldsA + 16384, w, l);
  stage64n(Bh,     k0 + 64, ldsB + 8192,  w, l);
  asm volatile("s_waitcnt vmcnt(6)" ::: "memory");
  __builtin_amdgcn_s_barrier();

  for (int i = 0; i < NT; ++i) {
    int buf = i & 1;
    const char* sAc = ldsA + buf * 16384;
    const char* sBc = ldsB + buf * 8192;
    bf16x8 a[2][2], b[4][2];
#pragma unroll
    for (int ii = 0; ii < 2; ++ii)
#pragma unroll
      for (int ks = 0; ks < 2; ++ks) {
        int row = w * 32 + ii * 16 + lr16;
        int kb  = ks * 64 + lk * 16;
        a[ii][ks] = *(const bf16x8*)(sAc + (row << 7) + (kb ^ ((row & 7) << 4)));
      }
#pragma unroll
    for (int jj = 0; jj < 4; ++jj)
#pragma unroll
      for (int ks = 0; ks < 2; ++ks) {
        int row = jj * 16 + lr16;
        int kb  = ks * 64 + lk * 16;
        b[jj][ks] = *(const bf16x8*)(sBc + (row << 7) + (kb ^ ((row & 7) << 4)));
      }
    asm volatile("s_waitcnt lgkmcnt(0)" ::: "memory");
    __builtin_amdgcn_sched_barrier(0);
    bool do_stage = (i + 2) < NT;
    if (do_stage) {
      __builtin_amdgcn_s_barrier();
      stage128(U,  s0, k0 + (i + 2) * 64, ldsA + buf * 16384, w, l);
      stage64n(Bh,     k0 + (i + 2) * 64, ldsB + buf * 8192,  w, l);
    }
#pragma unroll
    for (int ks = 0; ks < 2; ++ks)
#pragma unroll
      for (int ii = 0; ii < 2; ++ii)
#pragma unroll
        for (int jj = 0; jj < 4; ++jj)
          acc[ii][jj] = __builtin_amdgcn_mfma_f32_16x16x32_bf16(
              a[ii][ks], b[jj][ks], acc[ii][jj], 0, 0, 0);
    if (i + 1 < NT) {
      if (do_stage) asm volatile("s_waitcnt vmcnt(6)" ::: "memory");
      else          asm volatile("s_waitcnt vmcnt(0)" ::: "memory");
      __builtin_amdgcn_s_barrier();
    }
  }
  float* Pb = P + (size_t)blockIdx.y * 65536;
#pragma unroll
  for (int ii = 0; ii < 2; ++ii)
#pragma unroll
    for (int jj = 0; jj < 4; ++jj) {
      int col  = jj * 16 + lr16;
      int rowb = s0 + w * 32 + ii * 16 + lk * 4;
#pragma unroll
      for (int q = 0; q < 4; ++q)
        Pb[(size_t)(rowb + q) * 64 + col] = acc[ii][jj][q];
    }
}

// ---------------------------------------------------------------------------
// Kernel 5: lr tail: u[s][4096+r] = bf16( sum_c P[c][s][r] ); zero 192-col pad.
// ---------------------------------------------------------------------------
__global__ void lr_reduce_kernel(const float* __restrict__ P, u16* __restrict__ u) {
  int idx = blockIdx.x * 256 + threadIdx.x;   // 0..65535
  float s = P[idx] + P[65536 + idx] + P[131072 + idx] + P[196608 + idx];
  int ss = idx >> 6, rr = idx & 63;
  u16* row = u + (size_t)ss * GK;
  row[4096 + rr] = f2bf_rne(s);
  row[4160 + rr] = 0;                         // K pad
  row[4224 + rr] = 0;
  row[4288 + rr] = 0;
}

// ---------------------------------------------------------------------------
// Kernel 6: GEMM partials, 256x256 tile, 8 waves (2 s-dir x 4 m-dir, wave tile
// 128x64), BK=64 double-buffered (128 KiB LDS, 1 block/CU), K-split 4
// (GK=4352 -> 17 tiles/split). XCD-aware block remap (bid%8 -> XCD): each XCD
// gets 4 m-tiles x 2 (s,g)-cells -> B panels fetched once, A panels twice.
// Iter: read 24 frags | lgkm0+bar | stage(i+2) | 64 MFMA (setprio) |
// vmcnt(8)+bar. Partials g=0,1 -> d_out (bf16), g=2,3 -> ws.
// ---------------------------------------------------------------------------
__global__ __launch_bounds__(512, 2) void gemm_kernel(
    const u16* __restrict__ A,    // u  [1024][GK]
    const u16* __restrict__ Bm,   // Wd [4096][GK]
    u16* __restrict__ zO,         // [1024][2][4096] bf16 (aliases d_out)
    u16* __restrict__ zW) {       // [1024][2][4096] bf16 (ws)
  __shared__ char lds[131072];    // A0 A1 (32KB each) | B0 B1 (32KB each)
  int t = threadIdx.x, w = t >> 6, l = t & 63;
  // XCD-aware decomposition of 256 blocks -> (x m-tile, y s-tile, g k-split)
  int b = blockIdx.x;
  int xcd = b & 7, slot = b >> 3;
  int cell = slot >> 4, j = slot & 15;
  int x = (xcd & 3) * 4 + (j & 3);            // 0..15
  int g = (xcd >> 2) + 2 * cell;              // 0..3
  int y = j >> 2;                             // 0..3
  int m0 = x * 256, s0 = y * 256;
  int wsd = w >> 2, wmd = w & 3;              // wave pos: s-dir 0..1, m-dir 0..3
  int lr16 = l & 15, lk = l >> 4;
  char* ldsA = lds;
  char* ldsB = lds + 65536;

  floatx4 acc[8][4];
#pragma unroll
  for (int i = 0; i < 8; ++i)
#pragma unroll
    for (int jq = 0; jq < 4; ++jq) acc[i][jq] = (floatx4){0.f, 0.f, 0.f, 0.f};

  const int NT = 17;                          // 17*64 = 1088 per split
  int kb0 = g * 1088;

  stage256(A,  s0, kb0,      ldsA,         w, l);
  stage256(Bm, m0, kb0,      ldsB,         w, l);
  stage256(A,  s0, kb0 + 64, ldsA + 32768, w, l);
  stage256(Bm, m0, kb0 + 64, ldsB + 32768, w, l);
  asm volatile("s_waitcnt vmcnt(8)" ::: "memory");   // tile 0 landed
  __builtin_amdgcn_s_barrier();

  for (int i = 0; i < NT; ++i) {
    int buf = i & 1;
    const char* sA = ldsA + buf * 32768;
    const char* sB = ldsB + buf * 32768;
    bf16x8 af[8][2], bf[4][2];
#pragma unroll
    for (int ii = 0; ii < 8; ++ii)
#pragma unroll
      for (int ks = 0; ks < 2; ++ks) {
        int row = wsd * 128 + ii * 16 + lr16;
        int kb  = ks * 64 + lk * 16;
        af[ii][ks] = *(const bf16x8*)(sA + (row << 7) + (kb ^ ((row & 7) << 4)));
      }
#pragma unroll
    for (int jj = 0; jj < 4; ++jj)
#pragma unroll
      for (int ks = 0; ks < 2; ++ks) {
        int row = wmd * 64 + jj * 16 + lr16;
        int kb  = ks * 64 + lk * 16;
        bf[jj][ks] = *(const bf16x8*)(sB + (row << 7) + (kb ^ ((row & 7) << 4)));
      }
    asm volatile("s_waitcnt lgkmcnt(0)" ::: "memory");
    __builtin_amdgcn_sched_barrier(0);
    __builtin_amdgcn_s_barrier();             // all waves done reading buf
    bool do_stage = (i + 2) < NT;             // block-uniform
    if (do_stage) {
      stage256(A,  s0, kb0 + (i + 2) * 64, ldsA + buf * 32768, w, l);
      stage256(Bm, m0, kb0 + (i + 2) * 64, ldsB + buf * 32768, w, l);
    }
    __builtin_amdgcn_s_setprio(1);
#pragma unroll
    for (int ks = 0; ks < 2; ++ks)
#pragma unroll
      for (int ii = 0; ii < 8; ++ii)
#pragma unroll
        for (int jj = 0; jj < 4; ++jj)
          acc[ii][jj] = __builtin_amdgcn_mfma_f32_16x16x32_bf16(
              af[ii][ks], bf[jj][ks], acc[ii][jj], 0, 0, 0);
    __builtin_amdgcn_s_setprio(0);
    if (i + 1 < NT) {
      if (do_stage) asm volatile("s_waitcnt vmcnt(8)" ::: "memory");
      else          asm volatile("s_waitcnt vmcnt(0)" ::: "memory");
      __builtin_amdgcn_s_barrier();
    }
  }
  // C/D layout: col = lane&15, row = (lane>>4)*4 + q
  u16* dst = (g < 2) ? zO : zW;
  int gg = g & 1;
#pragma unroll
  for (int ii = 0; ii < 8; ++ii)
#pragma unroll
    for (int jj = 0; jj < 4; ++jj) {
      int col  = m0 + wmd * 64 + jj * 16 + lr16;
      int rowb = s0 + wsd * 128 + ii * 16 + lk * 4;
#pragma unroll
      for (int q = 0; q < 4; ++q)
        dst[(size_t)(rowb + q) * 8192 + gg * 4096 + col] = f2bf_rne(acc[ii][jj][q]);
    }
}

// ---------------------------------------------------------------------------
// Kernel 7: out[s][i] = (Wscale/263.68)*SV[i]*H(sum of 4 partials)[i]
// zO aliases out rows: block s reads exactly the region it later overwrites.
// ---------------------------------------------------------------------------
__global__ __launch_bounds__(256) void final_kernel(const float* __restrict__ SV,
                                                    const float* __restrict__ WscaleP,
                                                    const u16* __restrict__ zW,
                                                    float* __restrict__ out) {
  __shared__ float X[4096];
  int s = blockIdx.x, t = threadIdx.x, l = t & 63, w = t >> 6;
  const u16* zr = (const u16*)out + (size_t)s * 8192;
  const u16* zw = zW + (size_t)s * 8192;
  float v[16];
#pragma unroll
  for (int k = 0; k < 16; ++k) {
    int i = (w * 16 + k) * 64 + l;
    v[k] = (bf2f(zr[i]) + bf2f(zr[4096 + i])) + (bf2f(zw[i]) + bf2f(zw[4096 + i]));
  }
  fwht4096_regs(v, X, w, l);
  float gscale = WscaleP[0] * (1.0f / 263.68f);
  float* orow = out + (size_t)s * 4096;
#pragma unroll
  for (int k = 0; k < 16; ++k) {
    int i = (w * 16 + k) * 64 + l;
    orow[i] = v[k] * gscale * SV[i];
  }
}

// ---------------------------------------------------------------------------
extern "C" void kernel_launch(void* const* d_in, const int* in_sizes, int n_in,
                              void* d_out, int out_size, void* d_ws, size_t ws_size,
                              hipStream_t stream) {
  const float* x      = (const float*)d_in[0];   // [1,1024,4096]
  const float* SU     = (const float*)d_in[1];   // [4096]
  const float* SV     = (const float*)d_in[2];   // [4096]
  const float* Wscale = (const float*)d_in[3];   // scalar
  const float* loraA  = (const float*)d_in[4];   // [4096,64]
  const float* loraB  = (const float*)d_in[5];   // [64,4096]
  const int*   Qidxs  = (const int*)d_in[6];     // [4096,512]
  const int*   grid   = (const int*)d_in[7];     // [256]
  float* out = (float*)d_out;

  char* ws = (char*)d_ws;
  u16* Wd = (u16*)ws;                                    // [4096][4352] = 35,651,584 B
  u16* u  = (u16*)(ws + 35651584);                       // [1024][4352] =  8,912,896 B
  u16* Bh = (u16*)(ws + 35651584 + 8912896);             // [64][4096]   =    524,288 B
  float* P = (float*)(ws + 35651584 + 8912896 + 524288); // [4][1024][64] = 1,048,576 B
  u16* zW = (u16*)(ws + 35651584 + 8912896 + 524288 + 1048576); // [1024][2][4096] bf16
  u16* zO = (u16*)out;                                   // [1024][2][4096] bf16, in-place

  decode_kernel<<<8192, 256, 0, stream>>>(Qidxs, grid, Wd);
  prep_lora_kernel<<<64, 256, 0, stream>>>(loraA, SV, Wscale, loraB, SU, Wd, Bh);
  fwht_u_kernel<<<1024, 256, 0, stream>>>(x, SU, u);
  dim3 lg(8, 4);
  lr_gemm_kernel<<<lg, 256, 0, stream>>>(u, Bh, P);
  lr_reduce_kernel<<<256, 256, 0, stream>>>(P, u);
  gemm_kernel<<<256, 512, 0, stream>>>(u, Wd, zO, zW);
  final_kernel<<<1024, 256, 0, stream>>>(SV, Wscale, zW, out);
}

// Round 8
// 94.544 us; speedup vs baseline: 1.0359x; 1.0359x over previous
//
#include <hip/hip_runtime.h>
#include <hip/hip_bf16.h>

typedef unsigned short u16;
typedef float  floatx4 __attribute__((ext_vector_type(4)));
typedef short  bf16x8  __attribute__((ext_vector_type(8)));

#define GK 4352   // 4096 + 64 lora cols + 192 zero pad (= 4 * 17 * 64)

__device__ __forceinline__ u16 f2bf_rne(float f) {
  union { float f; unsigned int u; } v; v.f = f;
  unsigned int r = v.u + 0x7FFFu + ((v.u >> 16) & 1u);
  return (u16)(r >> 16);
}
__device__ __forceinline__ float bf2f(u16 h) {
  union { unsigned int u; float f; } v; v.u = ((unsigned int)h) << 16;
  return v.f;
}

// ===========================================================================
// In-register FWHT-4096 per block (4 waves): H4096 = H64(rows) (x) H64(cols).
// ===========================================================================
__device__ __forceinline__ void fwht4096_regs(float v[16], float* X, int w, int l) {
#pragma unroll
  for (int h = 1; h < 64; h <<= 1) {
#pragma unroll
    for (int k = 0; k < 16; ++k) {
      float o = __shfl_xor(v[k], h, 64);
      v[k] = (l & h) ? (o - v[k]) : (v[k] + o);
    }
  }
#pragma unroll
  for (int k = 0; k < 16; ++k) X[(w * 16 + k) * 64 + l] = v[k];
  __syncthreads();
  float s4 = (w & 1) ? -1.f : 1.f;
  float s5 = (w & 2) ? -1.f : 1.f;
#pragma unroll
  for (int k = 0; k < 16; ++k) {
    float x00 = X[(k     ) * 64 + l];
    float x01 = X[(k + 16) * 64 + l];
    float x10 = X[(k + 32) * 64 + l];
    float x11 = X[(k + 48) * 64 + l];
    v[k] = (x00 + s4 * x01) + s5 * (x10 + s4 * x11);
  }
#pragma unroll
  for (int h = 1; h < 16; h <<= 1) {
#pragma unroll
    for (int k = 0; k < 16; ++k) {
      if (!(k & h)) { float a = v[k], b = v[k ^ h]; v[k] = a + b; v[k ^ h] = a - b; }
    }
  }
}

// ---------------------------------------------------------------------------
// Kernel 1: decode E8P -> integer weights (exact in bf16), pitched rows of GK.
// ---------------------------------------------------------------------------
__global__ void decode_kernel(const int* __restrict__ codes,
                              const int* __restrict__ grid,
                              u16* __restrict__ Wd) {
  __shared__ int sgrid[256];
  int t = threadIdx.x;
  sgrid[t] = grid[t & 255];
  __syncthreads();
  int idx = blockIdx.x * 256 + t;            // 0 .. 4096*512-1
  int c = codes[idx];
  int abs_idx   = c & 255;
  int sign_bits = (c >> 8) & 127;
  int dlt       = 2 * ((c >> 15) & 1) - 1;   // 4*delta = ±1
  int packed    = sgrid[abs_idx];
  int par       = __popc(sign_bits) & 1;
  u16 w[8];
#pragma unroll
  for (int j = 0; j < 8; ++j) {
    int nib = (packed >> (4 * j)) & 15;
    int neg = (j < 7) ? ((sign_bits >> j) & 1) : par;
    int val = (neg ? -2 * nib : 2 * nib) + dlt;
    w[j] = f2bf_rne((float)val);             // exact: |val| <= 29
  }
  uint4 pk;
  pk.x = (unsigned)w[0] | ((unsigned)w[1] << 16);
  pk.y = (unsigned)w[2] | ((unsigned)w[3] << 16);
  pk.z = (unsigned)w[4] | ((unsigned)w[5] << 16);
  pk.w = (unsigned)w[6] | ((unsigned)w[7] << 16);
  int m = idx >> 9, g = idx & 511;
  ((uint4*)Wd)[(size_t)m * (GK / 8) + g] = pk;   // GK/8 = 544 uint4 per row
}

// ---------------------------------------------------------------------------
// Kernel 2 (fused): per block r (64 blocks):
//  (a) Wd[:,4096+r] = bf16( (0.8*263.68/(4096*Wscale)) * H_M(SV o loraA[:,r]) )
//  (b) zero Wd rows [64r,64r+64) cols 4160..4351 (K pad)
//  (c) Bh[r][:] = bf16( Hnorm(loraB[r] o SU) )   (Parseval: lr = u . Bh)
// ---------------------------------------------------------------------------
__global__ __launch_bounds__(256) void prep_lora_kernel(
    const float* __restrict__ loraA, const float* __restrict__ SV,
    const float* __restrict__ WscaleP, const float* __restrict__ loraB,
    const float* __restrict__ SU, u16* __restrict__ Wd, u16* __restrict__ Bh) {
  __shared__ float X[4096];
  int r = blockIdx.x, t = threadIdx.x, l = t & 63, w = t >> 6;
  float v[16];
#pragma unroll
  for (int k = 0; k < 16; ++k) {
    int i = (w * 16 + k) * 64 + l;
    v[k] = loraA[(size_t)i * 64 + r] * SV[i];
  }
  fwht4096_regs(v, X, w, l);
  float factor = (0.8f * 263.68f / 4096.0f) / WscaleP[0];
#pragma unroll
  for (int k = 0; k < 16; ++k) {
    int i = (w * 16 + k) * 64 + l;
    Wd[(size_t)i * GK + 4096 + r] = f2bf_rne(v[k] * factor);
  }
  {
    uint4 zv = make_uint4(0, 0, 0, 0);
#pragma unroll
    for (int j = 0; j < 6; ++j) {
      int idx = t + 256 * j;                 // 0..1535
      int row = idx / 24, cs = idx % 24;
      uint4* p = (uint4*)(Wd + (size_t)(r * 64 + row) * GK + 4160) + cs;
      *p = zv;
    }
  }
  __syncthreads();
#pragma unroll
  for (int k = 0; k < 16; ++k) {
    int i = (w * 16 + k) * 64 + l;
    v[k] = loraB[(size_t)r * 4096 + i] * SU[i];
  }
  fwht4096_regs(v, X, w, l);
#pragma unroll
  for (int k = 0; k < 16; ++k) {
    int i = (w * 16 + k) * 64 + l;
    Bh[(size_t)r * 4096 + i] = f2bf_rne(v[k] * 0.015625f);
  }
}

// ---------------------------------------------------------------------------
// Kernel 3: u[s][0..4095] = bf16( H(x[s] o SU) / 64 )
// ---------------------------------------------------------------------------
__global__ __launch_bounds__(256) void fwht_u_kernel(const float* __restrict__ x,
                                                     const float* __restrict__ SU,
                                                     u16* __restrict__ u) {
  __shared__ float X[4096];
  int s = blockIdx.x, t = threadIdx.x, l = t & 63, w = t >> 6;
  const float* xr = x + (size_t)s * 4096;
  float v[16];
#pragma unroll
  for (int k = 0; k < 16; ++k) {
    int i = (w * 16 + k) * 64 + l;
    v[k] = xr[i] * SU[i];
  }
  fwht4096_regs(v, X, w, l);
  u16* ur = u + (size_t)s * GK;
#pragma unroll
  for (int k = 0; k < 16; ++k) {
    int i = (w * 16 + k) * 64 + l;
    ur[i] = f2bf_rne(v[k] * 0.015625f);
  }
}

// ---------------------------------------------------------------------------
// Staging helpers (16B global_load_lds, XOR-swizzled source; verified r2-r7)
// ---------------------------------------------------------------------------
// 128 rows x 64 cols, 4-wave block, pitch GK (lr_gemm A)
__device__ __forceinline__ void stage128(const u16* __restrict__ src, int rowBase,
                                         int kt, char* ldsBase, int wg, int l) {
#pragma unroll
  for (int it = 0; it < 4; ++it) {
    int ci  = it * 4 + wg;
    int row = ci * 8 + (l >> 3);
    int cg  = (l & 7) ^ ((l >> 3) & 7);
    const u16* gp = src + (size_t)(rowBase + row) * GK + kt + cg * 8;
    __builtin_amdgcn_global_load_lds(
        (const __attribute__((address_space(1))) void*)gp,
        (__attribute__((address_space(3))) void*)(ldsBase + ci * 1024), 16, 0, 0);
  }
}
// 64 rows x 64 cols, 4-wave block, pitch 4096 (lr_gemm Bh)
__device__ __forceinline__ void stage64n(const u16* __restrict__ src,
                                         int kt, char* ldsBase, int wg, int l) {
#pragma unroll
  for (int it = 0; it < 2; ++it) {
    int ci  = it * 4 + wg;
    int row = ci * 8 + (l >> 3);
    int cg  = (l & 7) ^ ((l >> 3) & 7);
    const u16* gp = src + (size_t)row * 4096 + kt + cg * 8;
    __builtin_amdgcn_global_load_lds(
        (const __attribute__((address_space(1))) void*)gp,
        (__attribute__((address_space(3))) void*)(ldsBase + ci * 1024), 16, 0, 0);
  }
}
// 128-row x 64-col HALF-tile, 8-wave (512 thr) block: 2 loads/thread, 16 KB.
__device__ __forceinline__ void stage_half(const u16* __restrict__ src, int rowBase,
                                           int kt, char* slotBase, int w, int l) {
#pragma unroll
  for (int it = 0; it < 2; ++it) {
    int ci  = it * 8 + w;                 // 16 chunks of 1KB
    int row = ci * 8 + (l >> 3);
    int cg  = (l & 7) ^ ((l >> 3) & 7);
    const u16* gp = src + (size_t)(rowBase + row) * GK + kt + cg * 8;
    __builtin_amdgcn_global_load_lds(
        (const __attribute__((address_space(1))) void*)gp,
        (__attribute__((address_space(3))) void*)(slotBase + ci * 1024), 16, 0, 0);
  }
}

// ---------------------------------------------------------------------------
// Kernel 4: lr partials. P[by][s][r] = sum_{k in chunk by} u[s,k]*Bh[r,k]
// ---------------------------------------------------------------------------
__global__ __launch_bounds__(256) void lr_gemm_kernel(
    const u16* __restrict__ U,    // [1024][GK]
    const u16* __restrict__ Bh,   // [64][4096]
    float* __restrict__ P) {      // [4][1024][64]
  __shared__ char lds[49152];     // A0|A1 (16KB each) + B0|B1 (8KB each)
  int t = threadIdx.x, w = t >> 6, l = t & 63;
  int s0 = blockIdx.x * 128, k0 = blockIdx.y * 1024;
  int lr16 = l & 15, lk = l >> 4;
  char* ldsA = lds;
  char* ldsB = lds + 32768;

  floatx4 acc[2][4];
#pragma unroll
  for (int i = 0; i < 2; ++i)
#pragma unroll
    for (int j = 0; j < 4; ++j) acc[i][j] = (floatx4){0.f, 0.f, 0.f, 0.f};

  const int NT = 16;   // 16 * 64 = 1024
  stage128(U,  s0, k0,      ldsA,         w, l);
  stage64n(Bh,     k0,      ldsB,         w, l);
  stage128(U,  s0, k0 + 64, ldsA + 16384, w, l);
  stage64n(Bh,     k0 + 64, ldsB + 8192,  w, l);
  asm volatile("s_waitcnt vmcnt(6)" ::: "memory");
  __builtin_amdgcn_s_barrier();

  for (int i = 0; i < NT; ++i) {
    int buf = i & 1;
    const char* sAc = ldsA + buf * 16384;
    const char* sBc = ldsB + buf * 8192;
    bf16x8 a[2][2], b[4][2];
#pragma unroll
    for (int ii = 0; ii < 2; ++ii)
#pragma unroll
      for (int ks = 0; ks < 2; ++ks) {
        int row = w * 32 + ii * 16 + lr16;
        int kb  = ks * 64 + lk * 16;
        a[ii][ks] = *(const bf16x8*)(sAc + (row << 7) + (kb ^ ((row & 7) << 4)));
      }
#pragma unroll
    for (int jj = 0; jj < 4; ++jj)
#pragma unroll
      for (int ks = 0; ks < 2; ++ks) {
        int row = jj * 16 + lr16;
        int kb  = ks * 64 + lk * 16;
        b[jj][ks] = *(const bf16x8*)(sBc + (row << 7) + (kb ^ ((row & 7) << 4)));
      }
    asm volatile("s_waitcnt lgkmcnt(0)" ::: "memory");
    __builtin_amdgcn_sched_barrier(0);
    bool do_stage = (i + 2) < NT;
    if (do_stage) {
      __builtin_amdgcn_s_barrier();
      stage128(U,  s0, k0 + (i + 2) * 64, ldsA + buf * 16384, w, l);
      stage64n(Bh,     k0 + (i + 2) * 64, ldsB + buf * 8192,  w, l);
    }
#pragma unroll
    for (int ks = 0; ks < 2; ++ks)
#pragma unroll
      for (int ii = 0; ii < 2; ++ii)
#pragma unroll
        for (int jj = 0; jj < 4; ++jj)
          acc[ii][jj] = __builtin_amdgcn_mfma_f32_16x16x32_bf16(
              a[ii][ks], b[jj][ks], acc[ii][jj], 0, 0, 0);
    if (i + 1 < NT) {
      if (do_stage) asm volatile("s_waitcnt vmcnt(6)" ::: "memory");
      else          asm volatile("s_waitcnt vmcnt(0)" ::: "memory");
      __builtin_amdgcn_s_barrier();
    }
  }
  float* Pb = P + (size_t)blockIdx.y * 65536;
#pragma unroll
  for (int ii = 0; ii < 2; ++ii)
#pragma unroll
    for (int jj = 0; jj < 4; ++jj) {
      int col  = jj * 16 + lr16;
      int rowb = s0 + w * 32 + ii * 16 + lk * 4;
#pragma unroll
      for (int q = 0; q < 4; ++q)
        Pb[(size_t)(rowb + q) * 64 + col] = acc[ii][jj][q];
    }
}

// ---------------------------------------------------------------------------
// Kernel 5: lr tail: u[s][4096+r] = bf16( sum_c P[c][s][r] ); zero 192-col pad.
// ---------------------------------------------------------------------------
__global__ void lr_reduce_kernel(const float* __restrict__ P, u16* __restrict__ u) {
  int idx = blockIdx.x * 256 + threadIdx.x;   // 0..65535
  float s = P[idx] + P[65536 + idx] + P[131072 + idx] + P[196608 + idx];
  int ss = idx >> 6, rr = idx & 63;
  u16* row = u + (size_t)ss * GK;
  row[4096 + rr] = f2bf_rne(s);
  row[4160 + rr] = 0;                         // K pad
  row[4224 + rr] = 0;
  row[4288 + rr] = 0;
}

// ---------------------------------------------------------------------------
// Kernel 6: GEMM partials, 256x256 tile, 8 waves (2 s-dir x 4 m-dir, wave
// tile 128x64), K-split 4, m201-style 8-PHASE schedule: LDS = 2buf x
// {A0,A1,B0,B1} 16KB half-tiles. Per 2-K-tile iter, 8 phases of
// {ds-read subtile | stage 1 half | barrier | lgkm0 | setprio1 | 16 MFMA |
// setprio0 | [vmcnt(4) @ ph4,ph8] | barrier}. Counted vmcnt never 0 in loop.
// Slot-free schedule (derived): buf.B free after ph2/ph6, buf.A after ph3/ph7.
// NT=17: last iter skips ph7/ph8 B-stages; 4-phase read-only tail for tile 16.
// ---------------------------------------------------------------------------
__device__ __forceinline__ void rda(bf16x8 (&dst)[4][2], const char* base, int roff,
                                    int lr16, int lk) {
#pragma unroll
  for (int ii = 0; ii < 4; ++ii)
#pragma unroll
    for (int ks = 0; ks < 2; ++ks) {
      int r = roff + ii * 16 + lr16;
      dst[ii][ks] = *(const bf16x8*)(base + (r << 7) +
          ((ks * 64 + lk * 16) ^ ((r & 7) << 4)));
    }
}
__device__ __forceinline__ void rdb(bf16x8 (&dst)[2][2], const char* base, int roff,
                                    int lr16, int lk) {
#pragma unroll
  for (int jj = 0; jj < 2; ++jj)
#pragma unroll
    for (int ks = 0; ks < 2; ++ks) {
      int r = roff + jj * 16 + lr16;
      dst[jj][ks] = *(const bf16x8*)(base + (r << 7) +
          ((ks * 64 + lk * 16) ^ ((r & 7) << 4)));
    }
}
template<int IO, int JO>
__device__ __forceinline__ void mfq(const bf16x8 (&af)[4][2], const bf16x8 (&bf)[2][2],
                                    floatx4 (&acc)[8][4]) {
  __builtin_amdgcn_s_setprio(1);
#pragma unroll
  for (int ks = 0; ks < 2; ++ks)
#pragma unroll
    for (int ii = 0; ii < 4; ++ii)
#pragma unroll
      for (int jj = 0; jj < 2; ++jj)
        acc[IO + ii][JO + jj] = __builtin_amdgcn_mfma_f32_16x16x32_bf16(
            af[ii][ks], bf[jj][ks], acc[IO + ii][JO + jj], 0, 0, 0);
  __builtin_amdgcn_s_setprio(0);
}
#define PH_PRE()  do { __builtin_amdgcn_s_barrier(); \
                       asm volatile("s_waitcnt lgkmcnt(0)" ::: "memory"); } while (0)
#define PH_POST() __builtin_amdgcn_s_barrier()

__global__ __launch_bounds__(512, 2) void gemm_kernel(
    const u16* __restrict__ A,    // u  [1024][GK]
    const u16* __restrict__ Bm,   // Wd [4096][GK]
    u16* __restrict__ zO,         // [1024][2][4096] bf16 (aliases d_out)
    u16* __restrict__ zW) {       // [1024][2][4096] bf16 (ws)
  __shared__ char lds[131072];    // buf0: A0 A1 B0 B1 | buf1: A0 A1 B0 B1 (16KB)
  int t = threadIdx.x, w = t >> 6, l = t & 63;
  // XCD-aware decomposition (verified r7: FETCH 50->36 MB)
  int b = blockIdx.x;
  int xcd = b & 7, slot = b >> 3;
  int cell = slot >> 4, j4 = slot & 15;
  int x = (xcd & 3) * 4 + (j4 & 3);           // m-tile 0..15
  int g = (xcd >> 2) + 2 * cell;              // k-split 0..3
  int y = j4 >> 2;                            // s-tile 0..3
  int m0 = x * 256, s0 = y * 256;
  int wsd = w >> 2, wmd = w & 3;              // wave pos: s-half, m-quarter
  int lr16 = l & 15, lk = l >> 4;
  int boff = (wmd & 1) * 64;                  // B row offset within half

  const char* A0b = lds + wsd * 16384;                    // buf0 A half (own)
  const char* B0b = lds + 32768 + (wmd >> 1) * 16384;     // buf0 B half (own)
  const char* A1b = lds + 65536 + wsd * 16384;            // buf1 A half
  const char* B1b = lds + 98304 + (wmd >> 1) * 16384;     // buf1 B half

  floatx4 acc[8][4];
#pragma unroll
  for (int i = 0; i < 8; ++i)
#pragma unroll
    for (int jq = 0; jq < 4; ++jq) acc[i][jq] = (floatx4){0.f, 0.f, 0.f, 0.f};

  int kb0 = g * 1088;                          // 17 tiles * 64 per split

  // Prologue: T0 all 4 halves + T1 B halves (12 loads/thread)
  stage_half(A,  s0,       kb0,      lds +      0, w, l);  // T0.A0
  stage_half(A,  s0 + 128, kb0,      lds +  16384, w, l);  // T0.A1
  stage_half(Bm, m0,       kb0,      lds +  32768, w, l);  // T0.B0
  stage_half(Bm, m0 + 128, kb0,      lds +  49152, w, l);  // T0.B1
  stage_half(Bm, m0,       kb0 + 64, lds +  98304, w, l);  // T1.B0
  stage_half(Bm, m0 + 128, kb0 + 64, lds + 114688, w, l);  // T1.B1
  asm volatile("s_waitcnt vmcnt(4)" ::: "memory");         // T0 landed
  __builtin_amdgcn_s_barrier();

  for (int j = 0; j < 8; ++j) {               // tiles 2j (buf0), 2j+1 (buf1)
    int kt1  = kb0 + (2 * j + 1) * 64;
    int ktn0 = kb0 + (2 * j + 2) * 64;
    int ktn1 = kb0 + (2 * j + 3) * 64;
    bf16x8 aF[4][2], aG[4][2], bF[2][2], bG[2][2];
    // ph1: read T0 {A m0-3, B n0-1}; stage T1.A0 -> buf1.A0
    rda(aF, A0b, 0, lr16, lk); rdb(bF, B0b, boff, lr16, lk);
    stage_half(A, s0, kt1, lds + 65536, w, l);
    PH_PRE(); mfq<0, 0>(aF, bF, acc); PH_POST();
    // ph2: read T0 {B n2-3}; stage T1.A1
    rdb(bG, B0b, boff + 32, lr16, lk);
    stage_half(A, s0 + 128, kt1, lds + 81920, w, l);
    PH_PRE(); mfq<0, 2>(aF, bG, acc); PH_POST();
    // ph3: read T0 {A m4-7}; stage (T0+2).B0 -> buf0.B0 (freed after ph2)
    rda(aG, A0b, 64, lr16, lk);
    stage_half(Bm, m0, ktn0, lds + 32768, w, l);
    PH_PRE(); mfq<4, 0>(aG, bF, acc); PH_POST();
    // ph4: stage (T0+2).B1; vmcnt(4) -> T1.A (ph1/ph2) landed
    stage_half(Bm, m0 + 128, ktn0, lds + 49152, w, l);
    PH_PRE(); mfq<4, 2>(aG, bG, acc);
    asm volatile("s_waitcnt vmcnt(4)" ::: "memory");
    PH_POST();
    // ph5: read T1 {A m0-3, B n0-1}; stage (T0+2).A0 (buf0.A freed after ph3)
    rda(aF, A1b, 0, lr16, lk); rdb(bF, B1b, boff, lr16, lk);
    stage_half(A, s0, ktn0, lds + 0, w, l);
    PH_PRE(); mfq<0, 0>(aF, bF, acc); PH_POST();
    // ph6: read T1 {B n2-3}; stage (T0+2).A1
    rdb(bG, B1b, boff + 32, lr16, lk);
    stage_half(A, s0 + 128, ktn0, lds + 16384, w, l);
    PH_PRE(); mfq<0, 2>(aF, bG, acc); PH_POST();
    // ph7: read T1 {A m4-7}; stage (T1+2).B0 (buf1.B freed after ph6)
    rda(aG, A1b, 64, lr16, lk);
    if (j < 7) stage_half(Bm, m0, ktn1, lds + 98304, w, l);
    PH_PRE(); mfq<4, 0>(aG, bF, acc); PH_POST();
    // ph8: stage (T1+2).B1; vmcnt(4) -> (T0+2).A (ph5/ph6) landed
    if (j < 7) stage_half(Bm, m0 + 128, ktn1, lds + 114688, w, l);
    PH_PRE(); mfq<4, 2>(aG, bG, acc);
    asm volatile("s_waitcnt vmcnt(4)" ::: "memory");
    PH_POST();
  }
  // Tail: tile 16 (buf0), staged during j=7 ph3-6; read-only 4 phases.
  asm volatile("s_waitcnt vmcnt(0)" ::: "memory");
  __builtin_amdgcn_s_barrier();
  {
    bf16x8 aF[4][2], aG[4][2], bF[2][2], bG[2][2];
    rda(aF, A0b, 0, lr16, lk); rdb(bF, B0b, boff, lr16, lk);
    PH_PRE(); mfq<0, 0>(aF, bF, acc); PH_POST();
    rdb(bG, B0b, boff + 32, lr16, lk);
    PH_PRE(); mfq<0, 2>(aF, bG, acc); PH_POST();
    rda(aG, A0b, 64, lr16, lk);
    PH_PRE(); mfq<4, 0>(aG, bF, acc); PH_POST();
    PH_PRE(); mfq<4, 2>(aG, bG, acc);
  }
  // C/D layout: col = lane&15, row = (lane>>4)*4 + q (verified r1-r7)
  u16* dst = (g < 2) ? zO : zW;
  int gg = g & 1;
#pragma unroll
  for (int ii = 0; ii < 8; ++ii)
#pragma unroll
    for (int jj = 0; jj < 4; ++jj) {
      int col  = m0 + wmd * 64 + jj * 16 + lr16;
      int rowb = s0 + wsd * 128 + ii * 16 + lk * 4;
#pragma unroll
      for (int q = 0; q < 4; ++q)
        dst[(size_t)(rowb + q) * 8192 + gg * 4096 + col] = f2bf_rne(acc[ii][jj][q]);
    }
}

// ---------------------------------------------------------------------------
// Kernel 7: out[s][i] = (Wscale/263.68)*SV[i]*H(sum of 4 partials)[i]
// zO aliases out rows: block s reads exactly the region it later overwrites.
// ---------------------------------------------------------------------------
__global__ __launch_bounds__(256) void final_kernel(const float* __restrict__ SV,
                                                    const float* __restrict__ WscaleP,
                                                    const u16* __restrict__ zW,
                                                    float* __restrict__ out) {
  __shared__ float X[4096];
  int s = blockIdx.x, t = threadIdx.x, l = t & 63, w = t >> 6;
  const u16* zr = (const u16*)out + (size_t)s * 8192;
  const u16* zw = zW + (size_t)s * 8192;
  float v[16];
#pragma unroll
  for (int k = 0; k < 16; ++k) {
    int i = (w * 16 + k) * 64 + l;
    v[k] = (bf2f(zr[i]) + bf2f(zr[4096 + i])) + (bf2f(zw[i]) + bf2f(zw[4096 + i]));
  }
  fwht4096_regs(v, X, w, l);
  float gscale = WscaleP[0] * (1.0f / 263.68f);
  float* orow = out + (size_t)s * 4096;
#pragma unroll
  for (int k = 0; k < 16; ++k) {
    int i = (w * 16 + k) * 64 + l;
    orow[i] = v[k] * gscale * SV[i];
  }
}

// ---------------------------------------------------------------------------
extern "C" void kernel_launch(void* const* d_in, const int* in_sizes, int n_in,
                              void* d_out, int out_size, void* d_ws, size_t ws_size,
                              hipStream_t stream) {
  const float* x      = (const float*)d_in[0];   // [1,1024,4096]
  const float* SU     = (const float*)d_in[1];   // [4096]
  const float* SV     = (const float*)d_in[2];   // [4096]
  const float* Wscale = (const float*)d_in[3];   // scalar
  const float* loraA  = (const float*)d_in[4];   // [4096,64]
  const float* loraB  = (const float*)d_in[5];   // [64,4096]
  const int*   Qidxs  = (const int*)d_in[6];     // [4096,512]
  const int*   grid   = (const int*)d_in[7];     // [256]
  float* out = (float*)d_out;

  char* ws = (char*)d_ws;
  u16* Wd = (u16*)ws;                                    // [4096][4352] = 35,651,584 B
  u16* u  = (u16*)(ws + 35651584);                       // [1024][4352] =  8,912,896 B
  u16* Bh = (u16*)(ws + 35651584 + 8912896);             // [64][4096]   =    524,288 B
  float* P = (float*)(ws + 35651584 + 8912896 + 524288); // [4][1024][64] = 1,048,576 B
  u16* zW = (u16*)(ws + 35651584 + 8912896 + 524288 + 1048576); // [1024][2][4096] bf16
  u16* zO = (u16*)out;                                   // [1024][2][4096] bf16, in-place

  decode_kernel<<<8192, 256, 0, stream>>>(Qidxs, grid, Wd);
  prep_lora_kernel<<<64, 256, 0, stream>>>(loraA, SV, Wscale, loraB, SU, Wd, Bh);
  fwht_u_kernel<<<1024, 256, 0, stream>>>(x, SU, u);
  dim3 lg(8, 4);
  lr_gemm_kernel<<<lg, 256, 0, stream>>>(u, Bh, P);
  lr_reduce_kernel<<<256, 256, 0, stream>>>(P, u);
  gemm_kernel<<<256, 512, 0, stream>>>(u, Wd, zO, zW);
  final_kernel<<<1024, 256, 0, stream>>>(SV, Wscale, zW, out);
}

// Round 9
// 80.562 us; speedup vs baseline: 1.2157x; 1.1736x over previous
//
#include <hip/hip_runtime.h>
#include <hip/hip_bf16.h>

typedef unsigned short u16;
typedef float  floatx4 __attribute__((ext_vector_type(4)));
typedef short  bf16x8  __attribute__((ext_vector_type(8)));

#define GK 4352   // 4096 + 64 lora cols + 192 zero pad (= 4 * 17 * 64)

__device__ __forceinline__ u16 f2bf_rne(float f) {
  union { float f; unsigned int u; } v; v.f = f;
  unsigned int r = v.u + 0x7FFFu + ((v.u >> 16) & 1u);
  return (u16)(r >> 16);
}
__device__ __forceinline__ float bf2f(u16 h) {
  union { unsigned int u; float f; } v; v.u = ((unsigned int)h) << 16;
  return v.f;
}

// ===========================================================================
// In-register FWHT-4096 per block (4 waves): H4096 = H64(rows) (x) H64(cols).
// ===========================================================================
__device__ __forceinline__ void fwht4096_regs(float v[16], float* X, int w, int l) {
#pragma unroll
  for (int h = 1; h < 64; h <<= 1) {
#pragma unroll
    for (int k = 0; k < 16; ++k) {
      float o = __shfl_xor(v[k], h, 64);
      v[k] = (l & h) ? (o - v[k]) : (v[k] + o);
    }
  }
#pragma unroll
  for (int k = 0; k < 16; ++k) X[(w * 16 + k) * 64 + l] = v[k];
  __syncthreads();
  float s4 = (w & 1) ? -1.f : 1.f;
  float s5 = (w & 2) ? -1.f : 1.f;
#pragma unroll
  for (int k = 0; k < 16; ++k) {
    float x00 = X[(k     ) * 64 + l];
    float x01 = X[(k + 16) * 64 + l];
    float x10 = X[(k + 32) * 64 + l];
    float x11 = X[(k + 48) * 64 + l];
    v[k] = (x00 + s4 * x01) + s5 * (x10 + s4 * x11);
  }
#pragma unroll
  for (int h = 1; h < 16; h <<= 1) {
#pragma unroll
    for (int k = 0; k < 16; ++k) {
      if (!(k & h)) { float a = v[k], b = v[k ^ h]; v[k] = a + b; v[k ^ h] = a - b; }
    }
  }
}

// ---------------------------------------------------------------------------
// Kernel 1 (fused): grid 9280 blocks, block-uniform branch:
//  bid 0..1023   : u[s] = bf16( H(x[s] o SU) / 64 )          (fwht_u)
//  bid 1024..1087: Wd tail col 4096+r, K-pad zero, Bh[r]      (prep_lora)
//  bid 1088..9279: decode E8P -> Wd integer weights (bf16)    (decode)
// ---------------------------------------------------------------------------
__global__ __launch_bounds__(256) void prep_all_kernel(
    const float* __restrict__ x, const float* __restrict__ SU,
    const float* __restrict__ SV, const float* __restrict__ WscaleP,
    const float* __restrict__ loraA, const float* __restrict__ loraB,
    const int* __restrict__ codes, const int* __restrict__ grid,
    u16* __restrict__ Wd, u16* __restrict__ u, u16* __restrict__ Bh) {
  __shared__ float X[4096];
  int bid = blockIdx.x, t = threadIdx.x, l = t & 63, w = t >> 6;

  if (bid < 1024) {
    // ---- fwht_u: s = bid ----
    int s = bid;
    const float* xr = x + (size_t)s * 4096;
    float v[16];
#pragma unroll
    for (int k = 0; k < 16; ++k) {
      int i = (w * 16 + k) * 64 + l;
      v[k] = xr[i] * SU[i];
    }
    fwht4096_regs(v, X, w, l);
    __syncthreads();                       // all lanes done reading X
    u16* Xu = (u16*)X;                     // bounce bf16 through LDS
#pragma unroll
    for (int k = 0; k < 16; ++k)
      Xu[(w * 16 + k) * 64 + l] = f2bf_rne(v[k] * 0.015625f);
    __syncthreads();
    u16* ur = u + (size_t)s * GK;
#pragma unroll
    for (int c = 0; c < 2; ++c) {          // vectorized 16B stores
      int j = (t + 256 * c) * 8;
      *(uint4*)(ur + j) = *(const uint4*)(Xu + j);
    }
  } else if (bid < 1088) {
    // ---- prep_lora: r = bid - 1024 ----
    int r = bid - 1024;
    float v[16];
#pragma unroll
    for (int k = 0; k < 16; ++k) {
      int i = (w * 16 + k) * 64 + l;
      v[k] = loraA[(size_t)i * 64 + r] * SV[i];
    }
    fwht4096_regs(v, X, w, l);
    float factor = (0.8f * 263.68f / 4096.0f) / WscaleP[0];
#pragma unroll
    for (int k = 0; k < 16; ++k) {
      int i = (w * 16 + k) * 64 + l;
      Wd[(size_t)i * GK + 4096 + r] = f2bf_rne(v[k] * factor);
    }
    {
      uint4 zv = make_uint4(0, 0, 0, 0);
#pragma unroll
      for (int j = 0; j < 6; ++j) {
        int idx = t + 256 * j;             // 0..1535
        int row = idx / 24, cs = idx % 24;
        uint4* p = (uint4*)(Wd + (size_t)(r * 64 + row) * GK + 4160) + cs;
        *p = zv;
      }
    }
    __syncthreads();
#pragma unroll
    for (int k = 0; k < 16; ++k) {
      int i = (w * 16 + k) * 64 + l;
      v[k] = loraB[(size_t)r * 4096 + i] * SU[i];
    }
    fwht4096_regs(v, X, w, l);
#pragma unroll
    for (int k = 0; k < 16; ++k) {
      int i = (w * 16 + k) * 64 + l;
      Bh[(size_t)r * 4096 + i] = f2bf_rne(v[k] * 0.015625f);
    }
  } else {
    // ---- decode: blocks (bid-1088) in 0..8191 ----
    int* sgrid = (int*)X;
    sgrid[t] = grid[t & 255];
    __syncthreads();
    int idx = (bid - 1088) * 256 + t;      // 0 .. 4096*512-1
    int c = codes[idx];
    int abs_idx   = c & 255;
    int sign_bits = (c >> 8) & 127;
    int dlt       = 2 * ((c >> 15) & 1) - 1;
    int packed    = sgrid[abs_idx];
    int par       = __popc(sign_bits) & 1;
    u16 wv[8];
#pragma unroll
    for (int j = 0; j < 8; ++j) {
      int nib = (packed >> (4 * j)) & 15;
      int neg = (j < 7) ? ((sign_bits >> j) & 1) : par;
      int val = (neg ? -2 * nib : 2 * nib) + dlt;
      wv[j] = f2bf_rne((float)val);        // exact: |val| <= 29
    }
    uint4 pk;
    pk.x = (unsigned)wv[0] | ((unsigned)wv[1] << 16);
    pk.y = (unsigned)wv[2] | ((unsigned)wv[3] << 16);
    pk.z = (unsigned)wv[4] | ((unsigned)wv[5] << 16);
    pk.w = (unsigned)wv[6] | ((unsigned)wv[7] << 16);
    int m = idx >> 9, g = idx & 511;
    ((uint4*)Wd)[(size_t)m * (GK / 8) + g] = pk;
  }
}

// ---------------------------------------------------------------------------
// Staging helpers (16B global_load_lds, XOR-swizzled source; verified r2-r8)
// ---------------------------------------------------------------------------
__device__ __forceinline__ void stage128(const u16* __restrict__ src, int rowBase,
                                         int kt, char* ldsBase, int wg, int l) {
#pragma unroll
  for (int it = 0; it < 4; ++it) {
    int ci  = it * 4 + wg;
    int row = ci * 8 + (l >> 3);
    int cg  = (l & 7) ^ ((l >> 3) & 7);
    const u16* gp = src + (size_t)(rowBase + row) * GK + kt + cg * 8;
    __builtin_amdgcn_global_load_lds(
        (const __attribute__((address_space(1))) void*)gp,
        (__attribute__((address_space(3))) void*)(ldsBase + ci * 1024), 16, 0, 0);
  }
}
__device__ __forceinline__ void stage64n(const u16* __restrict__ src,
                                         int kt, char* ldsBase, int wg, int l) {
#pragma unroll
  for (int it = 0; it < 2; ++it) {
    int ci  = it * 4 + wg;
    int row = ci * 8 + (l >> 3);
    int cg  = (l & 7) ^ ((l >> 3) & 7);
    const u16* gp = src + (size_t)row * 4096 + kt + cg * 8;
    __builtin_amdgcn_global_load_lds(
        (const __attribute__((address_space(1))) void*)gp,
        (__attribute__((address_space(3))) void*)(ldsBase + ci * 1024), 16, 0, 0);
  }
}
// 128-row x 64-col HALF-tile, 8-wave (512 thr) block: 2 loads/thread, 16 KB.
__device__ __forceinline__ void stage_half(const u16* __restrict__ src, int rowBase,
                                           int kt, char* slotBase, int w, int l) {
#pragma unroll
  for (int it = 0; it < 2; ++it) {
    int ci  = it * 8 + w;                 // 16 chunks of 1KB
    int row = ci * 8 + (l >> 3);
    int cg  = (l & 7) ^ ((l >> 3) & 7);
    const u16* gp = src + (size_t)(rowBase + row) * GK + kt + cg * 8;
    __builtin_amdgcn_global_load_lds(
        (const __attribute__((address_space(1))) void*)gp,
        (__attribute__((address_space(3))) void*)(slotBase + ci * 1024), 16, 0, 0);
  }
}

// ---------------------------------------------------------------------------
// Kernel 2: lr partials. P[by][s][r] = sum_{k in chunk by} u[s,k]*Bh[r,k]
// ---------------------------------------------------------------------------
__global__ __launch_bounds__(256) void lr_gemm_kernel(
    const u16* __restrict__ U,    // [1024][GK]
    const u16* __restrict__ Bh,   // [64][4096]
    float* __restrict__ P) {      // [4][1024][64]
  __shared__ char lds[49152];     // A0|A1 (16KB each) + B0|B1 (8KB each)
  int t = threadIdx.x, w = t >> 6, l = t & 63;
  int s0 = blockIdx.x * 128, k0 = blockIdx.y * 1024;
  int lr16 = l & 15, lk = l >> 4;
  char* ldsA = lds;
  char* ldsB = lds + 32768;

  floatx4 acc[2][4];
#pragma unroll
  for (int i = 0; i < 2; ++i)
#pragma unroll
    for (int j = 0; j < 4; ++j) acc[i][j] = (floatx4){0.f, 0.f, 0.f, 0.f};

  const int NT = 16;   // 16 * 64 = 1024
  stage128(U,  s0, k0,      ldsA,         w, l);
  stage64n(Bh,     k0,      ldsB,         w, l);
  stage128(U,  s0, k0 + 64, ldsA + 16384, w, l);
  stage64n(Bh,     k0 + 64, ldsB + 8192,  w, l);
  asm volatile("s_waitcnt vmcnt(6)" ::: "memory");
  __builtin_amdgcn_s_barrier();

  for (int i = 0; i < NT; ++i) {
    int buf = i & 1;
    const char* sAc = ldsA + buf * 16384;
    const char* sBc = ldsB + buf * 8192;
    bf16x8 a[2][2], b[4][2];
#pragma unroll
    for (int ii = 0; ii < 2; ++ii)
#pragma unroll
      for (int ks = 0; ks < 2; ++ks) {
        int row = w * 32 + ii * 16 + lr16;
        int kb  = ks * 64 + lk * 16;
        a[ii][ks] = *(const bf16x8*)(sAc + (row << 7) + (kb ^ ((row & 7) << 4)));
      }
#pragma unroll
    for (int jj = 0; jj < 4; ++jj)
#pragma unroll
      for (int ks = 0; ks < 2; ++ks) {
        int row = jj * 16 + lr16;
        int kb  = ks * 64 + lk * 16;
        b[jj][ks] = *(const bf16x8*)(sBc + (row << 7) + (kb ^ ((row & 7) << 4)));
      }
    asm volatile("s_waitcnt lgkmcnt(0)" ::: "memory");
    __builtin_amdgcn_sched_barrier(0);
    bool do_stage = (i + 2) < NT;
    if (do_stage) {
      __builtin_amdgcn_s_barrier();
      stage128(U,  s0, k0 + (i + 2) * 64, ldsA + buf * 16384, w, l);
      stage64n(Bh,     k0 + (i + 2) * 64, ldsB + buf * 8192,  w, l);
    }
#pragma unroll
    for (int ks = 0; ks < 2; ++ks)
#pragma unroll
      for (int ii = 0; ii < 2; ++ii)
#pragma unroll
        for (int jj = 0; jj < 4; ++jj)
          acc[ii][jj] = __builtin_amdgcn_mfma_f32_16x16x32_bf16(
              a[ii][ks], b[jj][ks], acc[ii][jj], 0, 0, 0);
    if (i + 1 < NT) {
      if (do_stage) asm volatile("s_waitcnt vmcnt(6)" ::: "memory");
      else          asm volatile("s_waitcnt vmcnt(0)" ::: "memory");
      __builtin_amdgcn_s_barrier();
    }
  }
  float* Pb = P + (size_t)blockIdx.y * 65536;
#pragma unroll
  for (int ii = 0; ii < 2; ++ii)
#pragma unroll
    for (int jj = 0; jj < 4; ++jj) {
      int col  = jj * 16 + lr16;
      int rowb = s0 + w * 32 + ii * 16 + lk * 4;
#pragma unroll
      for (int q = 0; q < 4; ++q)
        Pb[(size_t)(rowb + q) * 64 + col] = acc[ii][jj][q];
    }
}

// ---------------------------------------------------------------------------
// Kernel 3: lr tail: u[s][4096+r] = bf16( sum_c P[c][s][r] ); zero 192-col pad.
// ---------------------------------------------------------------------------
__global__ void lr_reduce_kernel(const float* __restrict__ P, u16* __restrict__ u) {
  int idx = blockIdx.x * 256 + threadIdx.x;   // 0..65535
  float s = P[idx] + P[65536 + idx] + P[131072 + idx] + P[196608 + idx];
  int ss = idx >> 6, rr = idx & 63;
  u16* row = u + (size_t)ss * GK;
  row[4096 + rr] = f2bf_rne(s);
  row[4160 + rr] = 0;                         // K pad
  row[4224 + rr] = 0;
  row[4288 + rr] = 0;
}

// ---------------------------------------------------------------------------
// Kernel 4: GEMM partials, 256x256 tile, 8 waves, K-split 4, 8-phase
// m201-style schedule (verified r8). Byte-identical to r8.
// ---------------------------------------------------------------------------
__device__ __forceinline__ void rda(bf16x8 (&dst)[4][2], const char* base, int roff,
                                    int lr16, int lk) {
#pragma unroll
  for (int ii = 0; ii < 4; ++ii)
#pragma unroll
    for (int ks = 0; ks < 2; ++ks) {
      int r = roff + ii * 16 + lr16;
      dst[ii][ks] = *(const bf16x8*)(base + (r << 7) +
          ((ks * 64 + lk * 16) ^ ((r & 7) << 4)));
    }
}
__device__ __forceinline__ void rdb(bf16x8 (&dst)[2][2], const char* base, int roff,
                                    int lr16, int lk) {
#pragma unroll
  for (int jj = 0; jj < 2; ++jj)
#pragma unroll
    for (int ks = 0; ks < 2; ++ks) {
      int r = roff + jj * 16 + lr16;
      dst[jj][ks] = *(const bf16x8*)(base + (r << 7) +
          ((ks * 64 + lk * 16) ^ ((r & 7) << 4)));
    }
}
template<int IO, int JO>
__device__ __forceinline__ void mfq(const bf16x8 (&af)[4][2], const bf16x8 (&bf)[2][2],
                                    floatx4 (&acc)[8][4]) {
  __builtin_amdgcn_s_setprio(1);
#pragma unroll
  for (int ks = 0; ks < 2; ++ks)
#pragma unroll
    for (int ii = 0; ii < 4; ++ii)
#pragma unroll
      for (int jj = 0; jj < 2; ++jj)
        acc[IO + ii][JO + jj] = __builtin_amdgcn_mfma_f32_16x16x32_bf16(
            af[ii][ks], bf[jj][ks], acc[IO + ii][JO + jj], 0, 0, 0);
  __builtin_amdgcn_s_setprio(0);
}
#define PH_PRE()  do { __builtin_amdgcn_s_barrier(); \
                       asm volatile("s_waitcnt lgkmcnt(0)" ::: "memory"); } while (0)
#define PH_POST() __builtin_amdgcn_s_barrier()

__global__ __launch_bounds__(512, 2) void gemm_kernel(
    const u16* __restrict__ A,    // u  [1024][GK]
    const u16* __restrict__ Bm,   // Wd [4096][GK]
    u16* __restrict__ zO,         // [1024][2][4096] bf16 (aliases d_out)
    u16* __restrict__ zW) {       // [1024][2][4096] bf16 (ws)
  __shared__ char lds[131072];    // buf0: A0 A1 B0 B1 | buf1: A0 A1 B0 B1 (16KB)
  int t = threadIdx.x, w = t >> 6, l = t & 63;
  int b = blockIdx.x;
  int xcd = b & 7, slot = b >> 3;
  int cell = slot >> 4, j4 = slot & 15;
  int x = (xcd & 3) * 4 + (j4 & 3);           // m-tile 0..15
  int g = (xcd >> 2) + 2 * cell;              // k-split 0..3
  int y = j4 >> 2;                            // s-tile 0..3
  int m0 = x * 256, s0 = y * 256;
  int wsd = w >> 2, wmd = w & 3;
  int lr16 = l & 15, lk = l >> 4;
  int boff = (wmd & 1) * 64;

  const char* A0b = lds + wsd * 16384;
  const char* B0b = lds + 32768 + (wmd >> 1) * 16384;
  const char* A1b = lds + 65536 + wsd * 16384;
  const char* B1b = lds + 98304 + (wmd >> 1) * 16384;

  floatx4 acc[8][4];
#pragma unroll
  for (int i = 0; i < 8; ++i)
#pragma unroll
    for (int jq = 0; jq < 4; ++jq) acc[i][jq] = (floatx4){0.f, 0.f, 0.f, 0.f};

  int kb0 = g * 1088;                          // 17 tiles * 64 per split

  stage_half(A,  s0,       kb0,      lds +      0, w, l);  // T0.A0
  stage_half(A,  s0 + 128, kb0,      lds +  16384, w, l);  // T0.A1
  stage_half(Bm, m0,       kb0,      lds +  32768, w, l);  // T0.B0
  stage_half(Bm, m0 + 128, kb0,      lds +  49152, w, l);  // T0.B1
  stage_half(Bm, m0,       kb0 + 64, lds +  98304, w, l);  // T1.B0
  stage_half(Bm, m0 + 128, kb0 + 64, lds + 114688, w, l);  // T1.B1
  asm volatile("s_waitcnt vmcnt(4)" ::: "memory");         // T0 landed
  __builtin_amdgcn_s_barrier();

  for (int j = 0; j < 8; ++j) {               // tiles 2j (buf0), 2j+1 (buf1)
    int kt1  = kb0 + (2 * j + 1) * 64;
    int ktn0 = kb0 + (2 * j + 2) * 64;
    int ktn1 = kb0 + (2 * j + 3) * 64;
    bf16x8 aF[4][2], aG[4][2], bF[2][2], bG[2][2];
    rda(aF, A0b, 0, lr16, lk); rdb(bF, B0b, boff, lr16, lk);
    stage_half(A, s0, kt1, lds + 65536, w, l);
    PH_PRE(); mfq<0, 0>(aF, bF, acc); PH_POST();
    rdb(bG, B0b, boff + 32, lr16, lk);
    stage_half(A, s0 + 128, kt1, lds + 81920, w, l);
    PH_PRE(); mfq<0, 2>(aF, bG, acc); PH_POST();
    rda(aG, A0b, 64, lr16, lk);
    stage_half(Bm, m0, ktn0, lds + 32768, w, l);
    PH_PRE(); mfq<4, 0>(aG, bF, acc); PH_POST();
    stage_half(Bm, m0 + 128, ktn0, lds + 49152, w, l);
    PH_PRE(); mfq<4, 2>(aG, bG, acc);
    asm volatile("s_waitcnt vmcnt(4)" ::: "memory");
    PH_POST();
    rda(aF, A1b, 0, lr16, lk); rdb(bF, B1b, boff, lr16, lk);
    stage_half(A, s0, ktn0, lds + 0, w, l);
    PH_PRE(); mfq<0, 0>(aF, bF, acc); PH_POST();
    rdb(bG, B1b, boff + 32, lr16, lk);
    stage_half(A, s0 + 128, ktn0, lds + 16384, w, l);
    PH_PRE(); mfq<0, 2>(aF, bG, acc); PH_POST();
    rda(aG, A1b, 64, lr16, lk);
    if (j < 7) stage_half(Bm, m0, ktn1, lds + 98304, w, l);
    PH_PRE(); mfq<4, 0>(aG, bF, acc); PH_POST();
    if (j < 7) stage_half(Bm, m0 + 128, ktn1, lds + 114688, w, l);
    PH_PRE(); mfq<4, 2>(aG, bG, acc);
    asm volatile("s_waitcnt vmcnt(4)" ::: "memory");
    PH_POST();
  }
  asm volatile("s_waitcnt vmcnt(0)" ::: "memory");
  __builtin_amdgcn_s_barrier();
  {
    bf16x8 aF[4][2], aG[4][2], bF[2][2], bG[2][2];
    rda(aF, A0b, 0, lr16, lk); rdb(bF, B0b, boff, lr16, lk);
    PH_PRE(); mfq<0, 0>(aF, bF, acc); PH_POST();
    rdb(bG, B0b, boff + 32, lr16, lk);
    PH_PRE(); mfq<0, 2>(aF, bG, acc); PH_POST();
    rda(aG, A0b, 64, lr16, lk);
    PH_PRE(); mfq<4, 0>(aG, bF, acc); PH_POST();
    PH_PRE(); mfq<4, 2>(aG, bG, acc);
  }
  u16* dst = (g < 2) ? zO : zW;
  int gg = g & 1;
#pragma unroll
  for (int ii = 0; ii < 8; ++ii)
#pragma unroll
    for (int jj = 0; jj < 4; ++jj) {
      int col  = m0 + wmd * 64 + jj * 16 + lr16;
      int rowb = s0 + wsd * 128 + ii * 16 + lk * 4;
#pragma unroll
      for (int q = 0; q < 4; ++q)
        dst[(size_t)(rowb + q) * 8192 + gg * 4096 + col] = f2bf_rne(acc[ii][jj][q]);
    }
}

// ---------------------------------------------------------------------------
// Kernel 5: out[s][i] = (Wscale/263.68)*SV[i]*H(sum of 4 partials)[i]
// Vectorized: uint4 plane loads -> sum -> LDS bounce -> FWHT layout.
// zO aliases out rows: all block reads complete before the first barrier,
// writes happen after -> race-free row-local aliasing.
// ---------------------------------------------------------------------------
__global__ __launch_bounds__(256) void final_kernel(const float* __restrict__ SV,
                                                    const float* __restrict__ WscaleP,
                                                    const u16* __restrict__ zW,
                                                    float* __restrict__ out) {
  __shared__ float X[4096];
  int s = blockIdx.x, t = threadIdx.x, l = t & 63, w = t >> 6;
  const u16* zr = (const u16*)out + (size_t)s * 8192;
  const u16* zw = zW + (size_t)s * 8192;
#pragma unroll
  for (int c = 0; c < 2; ++c) {
    int j = (t + 256 * c) * 8;
    uint4 a0 = *(const uint4*)(zr + j);
    uint4 a1 = *(const uint4*)(zr + 4096 + j);
    uint4 b0 = *(const uint4*)(zw + j);
    uint4 b1 = *(const uint4*)(zw + 4096 + j);
    const unsigned* pa0 = (const unsigned*)&a0;
    const unsigned* pa1 = (const unsigned*)&a1;
    const unsigned* pb0 = (const unsigned*)&b0;
    const unsigned* pb1 = (const unsigned*)&b1;
#pragma unroll
    for (int q = 0; q < 4; ++q) {
      X[j + 2 * q] = (bf2f((u16)pa0[q]) + bf2f((u16)pa1[q])) +
                     (bf2f((u16)pb0[q]) + bf2f((u16)pb1[q]));
      X[j + 2 * q + 1] = (bf2f((u16)(pa0[q] >> 16)) + bf2f((u16)(pa1[q] >> 16))) +
                         (bf2f((u16)(pb0[q] >> 16)) + bf2f((u16)(pb1[q] >> 16)));
    }
  }
  __syncthreads();
  float v[16];
#pragma unroll
  for (int k = 0; k < 16; ++k) v[k] = X[(w * 16 + k) * 64 + l];
  __syncthreads();                  // X free before fwht's internal write
  fwht4096_regs(v, X, w, l);
  float gscale = WscaleP[0] * (1.0f / 263.68f);
  float* orow = out + (size_t)s * 4096;
#pragma unroll
  for (int k = 0; k < 16; ++k) {
    int i = (w * 16 + k) * 64 + l;
    orow[i] = v[k] * gscale * SV[i];
  }
}

// ---------------------------------------------------------------------------
extern "C" void kernel_launch(void* const* d_in, const int* in_sizes, int n_in,
                              void* d_out, int out_size, void* d_ws, size_t ws_size,
                              hipStream_t stream) {
  const float* x      = (const float*)d_in[0];   // [1,1024,4096]
  const float* SU     = (const float*)d_in[1];   // [4096]
  const float* SV     = (const float*)d_in[2];   // [4096]
  const float* Wscale = (const float*)d_in[3];   // scalar
  const float* loraA  = (const float*)d_in[4];   // [4096,64]
  const float* loraB  = (const float*)d_in[5];   // [64,4096]
  const int*   Qidxs  = (const int*)d_in[6];     // [4096,512]
  const int*   grid   = (const int*)d_in[7];     // [256]
  float* out = (float*)d_out;

  char* ws = (char*)d_ws;
  u16* Wd = (u16*)ws;                                    // [4096][4352] = 35,651,584 B
  u16* u  = (u16*)(ws + 35651584);                       // [1024][4352] =  8,912,896 B
  u16* Bh = (u16*)(ws + 35651584 + 8912896);             // [64][4096]   =    524,288 B
  float* P = (float*)(ws + 35651584 + 8912896 + 524288); // [4][1024][64] = 1,048,576 B
  u16* zW = (u16*)(ws + 35651584 + 8912896 + 524288 + 1048576); // [1024][2][4096] bf16
  u16* zO = (u16*)out;                                   // [1024][2][4096] bf16, in-place

  prep_all_kernel<<<9280, 256, 0, stream>>>(x, SU, SV, Wscale, loraA, loraB,
                                            Qidxs, grid, Wd, u, Bh);
  dim3 lg(8, 4);
  lr_gemm_kernel<<<lg, 256, 0, stream>>>(u, Bh, P);
  lr_reduce_kernel<<<256, 256, 0, stream>>>(P, u);
  gemm_kernel<<<256, 512, 0, stream>>>(u, Wd, zO, zW);
  final_kernel<<<1024, 256, 0, stream>>>(SV, Wscale, zW, out);
}